// Round 12
// baseline (153.753 us; speedup 1.0000x reference)
//
#include <hip/hip_runtime.h>
#include <math.h>

// ---- problem constants ----
#define B_ 2
#define S_ 2048
#define DM_ 2048
#define H_ 16
#define HKV_ 4
#define D_ 128
#define NKV_ 512           // HKV*D
#define M_ 4096            // B*S
#define CHK_ 32            // chunk length
#define NC_ 64             // S/CHK
#define SCALE_ 0.08838834764831845f
#define CLAMP_ 0.95f

typedef unsigned short u16;
typedef u16 ushortx8 __attribute__((ext_vector_type(8)));
typedef __bf16 bf16x8 __attribute__((ext_vector_type(8)));
typedef float f32x4 __attribute__((ext_vector_type(4)));

#define ASYNC16(gsrc, ldst) \
  __builtin_amdgcn_global_load_lds((const __attribute__((address_space(1))) void*)(gsrc), \
                                   (__attribute__((address_space(3))) void*)(ldst), 16, 0, 0)
#define SBAR()    __builtin_amdgcn_s_barrier()
#define WAITV(n)  asm volatile("s_waitcnt vmcnt(" #n ")" ::: "memory")
#define LGKM0()   asm volatile("s_waitcnt lgkmcnt(0)" ::: "memory")

__device__ __forceinline__ u16 f2b(float x){
  unsigned u = __float_as_uint(x);
  return (u16)((u + 0x7FFFu + ((u >> 16) & 1u)) >> 16);
}
__device__ __forceinline__ u16 f2bu(float x){           // round-half-up (cheap, staging only)
  return (u16)((__float_as_uint(x) + 0x8000u) >> 16);
}
__device__ __forceinline__ float b2f(u16 h){
  return __uint_as_float(((unsigned)h) << 16);
}
__device__ __forceinline__ bf16x8 ld8(const u16* p){
  return __builtin_bit_cast(bf16x8, *(const ushortx8*)p);
}
__device__ __forceinline__ f32x4 mfma16(bf16x8 a, bf16x8 b, f32x4 c){
  return __builtin_amdgcn_mfma_f32_16x16x32_bf16(a, b, c, 0, 0, 0);
}
__device__ __forceinline__ ushort4 pk4(float4 f){
  ushort4 o; o.x = f2bu(f.x); o.y = f2bu(f.y); o.z = f2bu(f.z); o.w = f2bu(f.w); return o;
}
// scale 8 bf16 elements by 8 f32 factors, re-round to bf16
__device__ __forceinline__ bf16x8 scale8(bf16x8 v, const float* s){
  ushortx8 u = __builtin_bit_cast(ushortx8, v);
  ushortx8 o;
  #pragma unroll
  for (int j = 0; j < 8; ++j) o[j] = f2b(b2f(u[j]) * s[j]);
  return __builtin_bit_cast(bf16x8, o);
}

// ---------------- f32 -> bf16 convert, W matrices only (hs handled inside k_gemm) ----------------
__global__ void k_cvt_w(const float* __restrict__ Wq, const float* __restrict__ Wk,
                        const float* __restrict__ Wv, u16* __restrict__ wcb){
  int i = blockIdx.x * blockDim.x + threadIdx.x;  // 8-elem unit; 786432 total
  const float* src; u16* dst;
  if (i < 524288)      { src = Wq + (size_t)i * 8;               dst = wcb + (size_t)i * 8; }
  else if (i < 655360) { int j = i - 524288; src = Wk + (size_t)j * 8; dst = wcb + 4194304 + (size_t)j * 8; }
  else                 { int j = i - 655360; src = Wv + (size_t)j * 8; dst = wcb + 5242880 + (size_t)j * 8; }
  const float4* p = (const float4*)src;
  float4 a = p[0], c = p[1];
  ushortx8 o;
  o[0]=f2b(a.x); o[1]=f2b(a.y); o[2]=f2b(a.z); o[3]=f2b(a.w);
  o[4]=f2b(c.x); o[5]=f2b(c.y); o[6]=f2b(c.z); o[7]=f2b(c.w);
  *(ushortx8*)dst = o;
}

// ---------------- 128x128x32 GEMM: A reg-staged from f32 hs (fused convert), W async bf16 ----------------
// 3-slot LDS ring (slot = A[128][32] + W[128][32] bf16 = 16 KiB). Per iter j:
//   WAITV(2) [retire W(j), A(j+1)-regs; leave W(j+1)] ; lgkm0 ; barrier ;
//   ds_write A(j+1)->slot(j+1) ; LDA f32 A(j+2)->regs ; ASYNC16 W(j+2)->slot(j+2) ;
//   ds_read frags slot(j) ; 16 MFMA.
__launch_bounds__(256, 2)
__global__ void k_gemm(const float* __restrict__ Af, const u16* __restrict__ W,
                       const float* __restrict__ bq, const float* __restrict__ bk,
                       const float* __restrict__ bv,
                       u16* __restrict__ qp, u16* __restrict__ kp,
                       float* __restrict__ gG, u16* __restrict__ vT){
  __shared__ u16 L[3 * 8192];          // 48 KiB
  const int tid = threadIdx.x;
  const int wid = tid >> 6, lane = tid & 63;
  const int m0 = blockIdx.y * 128, n0 = blockIdx.x * 128;
  const int wr = (wid >> 1) * 64, wc = (wid & 1) * 64;
  const int lr = lane & 15, lk = (lane >> 4) * 8;

  int offA[4], offB[4];
  #pragma unroll
  for (int m = 0; m < 4; ++m) offA[m] = (wr + m * 16 + lr) * 32 + lk;
  #pragma unroll
  for (int n = 0; n < 4; ++n) offB[n] = (wc + n * 16 + lr) * 32 + lk;

  // A f32 source: lane covers rows wid*32+(lane>>3)+{0,8,16,24}, cols (lane&7)*4
  const float* gAf = Af + (size_t)(m0 + wid * 32 + (lane >> 3)) * DM_ + (lane & 7) * 4;
  const int aoff = (wid * 32 + (lane >> 3)) * 32 + (lane & 7) * 4;   // LDS elem offset (A part)
  // W staging (async, linear)
  const u16* gW = W + (size_t)(n0 + wid * 32 + (lane >> 2)) * DM_ + (lane & 3) * 8;
  const int foW = wid * 1024;

#define LDA(R, kk0) \
  R##0 = *(const float4*)(gAf + (kk0)); \
  R##1 = *(const float4*)(gAf +  8 * DM_ + (kk0)); \
  R##2 = *(const float4*)(gAf + 16 * DM_ + (kk0)); \
  R##3 = *(const float4*)(gAf + 24 * DM_ + (kk0))
#define DSW(db, R) { \
  u16* p_ = L + (db) + aoff; \
  *(ushort4*)(p_ +   0) = pk4(R##0); \
  *(ushort4*)(p_ + 256) = pk4(R##1); \
  *(ushort4*)(p_ + 512) = pk4(R##2); \
  *(ushort4*)(p_ + 768) = pk4(R##3); }
#define STGW(db, kk0) \
  ASYNC16(gW + (kk0),            L + (db) + 4096 + foW); \
  ASYNC16(gW + 16 * DM_ + (kk0), L + (db) + 4096 + foW + 512)

  float4 rA0, rA1, rA2, rA3, rB0, rB1, rB2, rB3;
  f32x4 acc[4][4] = {};

  // prologue: A(0)->rA, W(0)->slot0, A(1)->rB, W(1)->slot1
  LDA(rA, 0);          // 4 vmem
  STGW(0, 0);          // 2
  LDA(rB, 32);         // 4
  STGW(8192, 32);      // 2  (12 outstanding)
  WAITV(8);            // retire A(0); [W0,A1,W1] remain
  DSW(0, rA);          // A(0) -> slot0

  int sA = 0, sB = 8192, sC = 16384;   // slots for tiles j, j+1, j+2
  for (int jj = 0; jj < 32; ++jj){
    const int j = jj * 2;
    {  // ---- iter j: DSW rB, reload rA ----
      WAITV(2); LGKM0(); SBAR();
      DSW(sB, rB);
      const int kn = ((j + 2 < 64) ? j + 2 : 63) * 32;
      LDA(rA, kn);
      STGW(sC, kn);
      bf16x8 af[4], bfv[4];
      #pragma unroll
      for (int m = 0; m < 4; ++m) af[m]  = ld8(L + sA + offA[m]);
      #pragma unroll
      for (int n = 0; n < 4; ++n) bfv[n] = ld8(L + sA + 4096 + offB[n]);
      #pragma unroll
      for (int m = 0; m < 4; ++m)
        #pragma unroll
        for (int n = 0; n < 4; ++n) acc[m][n] = mfma16(af[m], bfv[n], acc[m][n]);
      int t = sA; sA = sB; sB = sC; sC = t;
    }
    {  // ---- iter j+1: DSW rA, reload rB ----
      WAITV(2); LGKM0(); SBAR();
      DSW(sB, rA);
      const int kn = ((j + 3 < 64) ? j + 3 : 63) * 32;
      LDA(rB, kn);
      STGW(sC, kn);
      bf16x8 af[4], bfv[4];
      #pragma unroll
      for (int m = 0; m < 4; ++m) af[m]  = ld8(L + sA + offA[m]);
      #pragma unroll
      for (int n = 0; n < 4; ++n) bfv[n] = ld8(L + sA + 4096 + offB[n]);
      #pragma unroll
      for (int m = 0; m < 4; ++m)
        #pragma unroll
        for (int n = 0; n < 4; ++n) acc[m][n] = mfma16(af[m], bfv[n], acc[m][n]);
      int t = sA; sA = sB; sB = sC; sC = t;
    }
  }
#undef LDA
#undef DSW
#undef STGW

  // ---- epilogue: per-region bias + activation (R1-proven) ----
  const int lg4 = lane >> 4;
  const int tn = blockIdx.x;
  if (tn < 16){                       // ---- q region: relu * scale ----
    #pragma unroll
    for (int i = 0; i < 4; ++i){
      const int rb = m0 + wr + i*16 + lg4*4;
      #pragma unroll
      for (int j = 0; j < 4; ++j){
        const int col = n0 + wc + j*16 + lr;
        const float bb = bq[col];
        #pragma unroll
        for (int r = 0; r < 4; ++r){
          float q = fmaxf(acc[i][j][r] + bb, 0.f) * SCALE_;
          qp[(size_t)(rb + r) * DM_ + col] = f2b(q);
        }
      }
    }
  } else if (tn < 20){                // ---- k region ----
    #pragma unroll
    for (int i = 0; i < 4; ++i){
      const int rb = m0 + wr + i*16 + lg4*4;
      #pragma unroll
      for (int j = 0; j < 4; ++j){
        const int cc = n0 - DM_ + wc + j*16 + lr;
        const float bb = bk[cc];
        #pragma unroll
        for (int r = 0; r < 4; ++r){
          float x = acc[i][j][r] + bb;
          float kf = fminf(1.f / (1.f + __expf(-x)), CLAMP_);
          kp[(size_t)(rb + r) * NKV_ + cc] = f2b(kf);
          gG[(size_t)(rb + r) * NKV_ + cc] = log1pf(-kf);
        }
      }
    }
  } else {                            // ---- v region: write transposed vT[b][kv][e][s] ----
    #pragma unroll
    for (int i = 0; i < 4; ++i){
      const int rb = m0 + wr + i*16 + lg4*4;
      const int bb_ = rb >> 11;
      const int srw = rb & 2047;
      #pragma unroll
      for (int j = 0; j < 4; ++j){
        const int cc = n0 - DM_ - NKV_ + wc + j*16 + lr;
        const float bias = bv[cc];
        const int kv = cc >> 7, e = cc & 127;
        ushort4 pk;
        pk.x = f2b(acc[i][j][0] + bias);
        pk.y = f2b(acc[i][j][1] + bias);
        pk.z = f2b(acc[i][j][2] + bias);
        pk.w = f2b(acc[i][j][3] + bias);
        *(ushort4*)(vT + (((size_t)(bb_ * HKV_ + kv) * D_ + e) * S_ + srw)) = pk;
      }
    }
  }
}

// ---------------- per-chunk inclusive cumsum of g (in place) + chunk decay ----------------
__global__ void k_cumsum(float* __restrict__ g, float* __restrict__ dec){
  const int c = blockIdx.x, b = blockIdx.z;
  const int col = blockIdx.y * 256 + threadIdx.x;   // 512 = kv*128+d
  const size_t base = ((size_t)b * S_ + (size_t)c * CHK_) * NKV_ + col;
  float v[CHK_];
  #pragma unroll
  for (int t = 0; t < CHK_; ++t) v[t] = g[base + (size_t)t * NKV_];
  float acc = 0.f;
  #pragma unroll
  for (int t = 0; t < CHK_; ++t){ acc += v[t]; v[t] = acc; }
  #pragma unroll
  for (int t = 0; t < CHK_; ++t) g[base + (size_t)t * NKV_] = v[t];
  const int kv = col >> 7, d = col & 127;
  dec[(((size_t)b * HKV_ + kv) * NC_ + c) * D_ + d] = __expf(acc);
}

// ---------------- per-chunk state contribution:  SSt[c][e][d] = sum_t v[t][e]*kf[t][d]*exp(G31-G_t) ----------------
__launch_bounds__(256, 2)
__global__ void k_dstate(const u16* __restrict__ kp, const float* __restrict__ G,
                         const u16* __restrict__ vT, u16* __restrict__ SSt){
  __shared__ float kex[CHK_][D_];
  __shared__ float vl[D_][CHK_ + 1];
  const int c = blockIdx.x, kv = blockIdx.y, b = blockIdx.z;
  const int tid = threadIdx.x;
  const int s0 = c * CHK_;
  const size_t gbase = ((size_t)b * S_ + s0) * NKV_ + kv * D_;
  for (int idx = tid; idx < CHK_ * D_; idx += 256){
    const int t = idx >> 7, d = idx & 127;
    const float Gt  = G[gbase + (size_t)t  * NKV_ + d];
    const float G31 = G[gbase + (size_t)31 * NKV_ + d];
    const float kf = b2f(kp[gbase + (size_t)t * NKV_ + d]);
    kex[t][d] = kf * __expf(G31 - Gt);
  }
  const size_t vbase = ((size_t)(b * HKV_ + kv) * D_) * S_ + s0;
  for (int idx = tid; idx < 512; idx += 256){
    const int e = idx >> 2, t8 = (idx & 3) * 8;
    ushortx8 vv = *(const ushortx8*)(vT + vbase + (size_t)e * S_ + t8);
    #pragma unroll
    for (int u = 0; u < 8; ++u) vl[e][t8 + u] = b2f(vv[u]);
  }
  __syncthreads();
  const int w = tid >> 6, lane = tid & 63;
  const int e = (w & 1) * 64 + lane;
  const int d0 = (w >> 1) * 64;
  float acc[64];
  #pragma unroll
  for (int i = 0; i < 64; ++i) acc[i] = 0.f;
  for (int t = 0; t < CHK_; ++t){
    const float vv = vl[e][t];
    const float4* kr = (const float4*)(&kex[t][d0]);
    #pragma unroll
    for (int i4 = 0; i4 < 16; ++i4){
      float4 kk = kr[i4];
      acc[i4*4+0] = fmaf(vv, kk.x, acc[i4*4+0]);
      acc[i4*4+1] = fmaf(vv, kk.y, acc[i4*4+1]);
      acc[i4*4+2] = fmaf(vv, kk.z, acc[i4*4+2]);
      acc[i4*4+3] = fmaf(vv, kk.w, acc[i4*4+3]);
    }
  }
  const size_t ob = (((size_t)(b * HKV_ + kv) * NC_ + c) * D_ + e) * D_ + d0;
  #pragma unroll
  for (int i8 = 0; i8 < 8; ++i8){
    ushortx8 o;
    #pragma unroll
    for (int u = 0; u < 8; ++u) o[u] = f2b(acc[i8*8 + u]);
    *(ushortx8*)(SSt + ob + i8*8) = o;
  }
}

// ---------------- elementwise scan over chunks (256 blocks x 128 thr, 1/CU) ----------------
__global__ void k_scan(u16* __restrict__ SSt, const float* __restrict__ dec){
  const int eg = blockIdx.x, kv = blockIdx.y, b = blockIdx.z;
  const int tid = threadIdx.x;
  const int e = eg * 4 + (tid >> 5);
  const int d4 = (tid & 31) * 4;
  const size_t base  = ((size_t)(b * HKV_ + kv) * NC_) * D_ * D_ + (size_t)e * D_ + d4;
  const size_t dbase = ((size_t)(b * HKV_ + kv) * NC_) * D_ + d4;
  float s0 = 0.f, s1 = 0.f, s2 = 0.f, s3 = 0.f;
  #pragma unroll 4
  for (int c = 0; c < NC_; ++c){
    const size_t off = base + (size_t)c * (D_ * D_);
    ushort4 dv = *(ushort4*)(SSt + off);
    float4 dc = *(const float4*)(dec + dbase + (size_t)c * D_);
    ushort4 wr;
    wr.x = f2b(s0); wr.y = f2b(s1); wr.z = f2b(s2); wr.w = f2b(s3);
    *(ushort4*)(SSt + off) = wr;
    s0 = s0 * dc.x + b2f(dv.x);
    s1 = s1 * dc.y + b2f(dv.y);
    s2 = s2 * dc.z + b2f(dv.z);
    s3 = s3 * dc.w + b2f(dv.w);
  }
}

// ---------------- output, per-kv blocks; 72.5 KB LDS -> 2 blocks/CU (R11-proven) ----------------
#define L_SB   0
#define L_QEF  16384
#define L_KE1  32768
#define L_SF   36864
#define LDS_OUT2_BYTES ((36864 + 256) * 2)
__global__ void __launch_bounds__(512)
k_out2(const u16* __restrict__ qp, const u16* __restrict__ kp,
       const float* __restrict__ G, const u16* __restrict__ vT,
       const u16* __restrict__ SSt, float* __restrict__ out){
  extern __shared__ u16 lds[];
  float* sFf = (float*)(lds + L_SF);
  const int c = blockIdx.x, kv = blockIdx.y, b = blockIdx.z;
  const int tid = threadIdx.x, wid = tid >> 6, lane = tid & 63;
  const int hh = wid >> 1, sub = wid & 1;
  const int s0 = c * CHK_;
  const int lr = lane & 15, lk = (lane >> 4) * 8;
  const size_t gb = ((size_t)b * S_ + s0) * NKV_ + kv * D_;
  const size_t qb0 = ((size_t)b * S_ + s0) * DM_ + (kv * 4) * D_;
  const size_t vb = ((size_t)(b * HKV_ + kv) * D_) * S_ + s0;

  {
    const u16* src = SSt + (((size_t)(b * HKV_ + kv) * NC_ + c) * (D_ * D_));
    #pragma unroll
    for (int is = 0; is < 4; ++is){
      const int fo = is * 4096 + wid * 512;
      ASYNC16(src + fo + lane * 8, lds + L_SB + fo);
    }
  }
  const int dmy = tid & 127;
  const float G15v = G[gb + (size_t)15 * NKV_ + dmy];
  if (tid < 128) sFf[tid] = __expf(-G15v);

  for (int idx = tid; idx < 32 * 128; idx += 512){
    const int t = idx >> 7;
    const float Gt = G[gb + (size_t)t * NKV_ + dmy];
    const float kf = b2f(kp[gb + (size_t)t * NKV_ + dmy]);
    const float eGt = __expf(Gt);
    float qv[4];
    #pragma unroll
    for (int q4 = 0; q4 < 4; ++q4) qv[q4] = b2f(qp[qb0 + (size_t)t * DM_ + q4 * D_ + dmy]);
    #pragma unroll
    for (int q4 = 0; q4 < 4; ++q4) lds[L_QEF + q4 * 4096 + idx] = f2b(qv[q4] * eGt);
    lds[L_KE1 + idx] = f2b(kf * __expf(G15v - Gt));
  }
  __syncthreads();

  float sreg[4][8];
  #pragma unroll
  for (int kd = 0; kd < 4; ++kd)
    #pragma unroll
    for (int j = 0; j < 8; ++j) sreg[kd][j] = sFf[kd * 32 + lk + j];

  const u16* QeF = lds + L_QEF + hh * 4096;
  const u16* KE1 = lds + L_KE1;
  f32x4 aU = {}, aL = {}, aO = {};
  if (sub == 0){
    #pragma unroll
    for (int kd = 0; kd < 4; ++kd){
      bf16x8 faU = ld8(&QeF[lr * 128 + kd * 32 + lk]);
      bf16x8 fbU = scale8(ld8(&KE1[lr * 128 + kd * 32 + lk]), sreg[kd]);
      aU = mfma16(faU, fbU, aU);
      bf16x8 faL = scale8(ld8(&QeF[(16 + lr) * 128 + kd * 32 + lk]), sreg[kd]);
      bf16x8 fbL = ld8(&KE1[(16 + lr) * 128 + kd * 32 + lk]);
      aL = mfma16(faL, fbL, aL);
    }
  } else {
    #pragma unroll
    for (int kd = 0; kd < 4; ++kd){
      bf16x8 fa = ld8(&QeF[(16 + lr) * 128 + kd * 32 + lk]);
      fa = scale8(fa, sreg[kd]);
      bf16x8 fb = ld8(&KE1[lr * 128 + kd * 32 + lk]);
      aO = mfma16(fa, fb, aO);
    }
  }
  __syncthreads();

  u16* Am = lds + L_KE1 + hh * 1024;
  if (sub == 0){
    #pragma unroll
    for (int r = 0; r < 4; ++r){
      const int rr = (lane >> 4) * 4 + r;
      float vU = aU[r]; if (lr > rr) vU = 0.f;
      Am[rr * 32 + lr] = f2b(vU);
      float vL = aL[r]; if (lr > rr) vL = 0.f;
      Am[(16 + rr) * 32 + 16 + lr] = f2b(vL);
    }
  } else {
    #pragma unroll
    for (int r = 0; r < 4; ++r){
      const int rr = (lane >> 4) * 4 + r;
      Am[(16 + rr) * 32 + lr] = f2b(aO[r]);
    }
    for (int i = lane; i < 256; i += 64) Am[(i >> 4) * 32 + 16 + (i & 15)] = 0;
  }
  __syncthreads();

  f32x4 o4[2][4] = {};
  const int ew = sub * 64;
  #pragma unroll
  for (int kd = 0; kd < 4; ++kd){
    bf16x8 fa0 = ld8(&QeF[(0  + lr) * 128 + kd * 32 + lk]);
    bf16x8 fa1 = ld8(&QeF[(16 + lr) * 128 + kd * 32 + lk]);
    #pragma unroll
    for (int j2 = 0; j2 < 4; ++j2){
      bf16x8 fb = ld8(&lds[L_SB + (ew + j2 * 16 + lr) * 128 + kd * 32 + lk]);
      o4[0][j2] = mfma16(fa0, fb, o4[0][j2]);
      o4[1][j2] = mfma16(fa1, fb, o4[1][j2]);
    }
  }
  {
    bf16x8 fa0 = ld8(&Am[lr * 32 + lk]);
    bf16x8 fa1 = ld8(&Am[(16 + lr) * 32 + lk]);
    #pragma unroll
    for (int j2 = 0; j2 < 4; ++j2){
      const u16* vr = vT + vb + (size_t)(ew + j2 * 16 + lr) * S_;
      bf16x8 fb = ld8(vr + lk);
      o4[0][j2] = mfma16(fa0, fb, o4[0][j2]);
      o4[1][j2] = mfma16(fa1, fb, o4[1][j2]);
    }
  }
  const int hD = (kv * 4 + hh) * D_;
  #pragma unroll
  for (int i2 = 0; i2 < 2; ++i2)
    #pragma unroll
    for (int j2 = 0; j2 < 4; ++j2)
      #pragma unroll
      for (int r = 0; r < 4; ++r){
        const int t = i2 * 16 + (lane >> 4) * 4 + r;
        const int e = ew + j2 * 16 + lr;
        out[((size_t)b * S_ + s0 + t) * DM_ + hD + e] = o4[i2][j2][r];
      }
}

// ---------------- host launch ----------------
extern "C" void kernel_launch(void* const* d_in, const int* in_sizes, int n_in,
                              void* d_out, int out_size, void* d_ws, size_t ws_size,
                              hipStream_t stream){
  const float* hs = (const float*)d_in[0];
  const float* Wq = (const float*)d_in[1];
  const float* bq = (const float*)d_in[2];
  const float* Wk = (const float*)d_in[3];
  const float* bk = (const float*)d_in[4];
  const float* Wv = (const float*)d_in[5];
  const float* bv = (const float*)d_in[6];
  char* ws = (char*)d_ws;
  u16*   wcb = (u16*)(ws + 16777216);
  u16*   qp  = (u16*)(ws + 29360128);
  u16*   kp  = (u16*)(ws + 46137344);
  float* gG  = (float*)(ws + 50331648);
  u16*   vT  = (u16*)(ws + 58720256);
  float* dec = (float*)(ws + 62914560);
  u16*   SSt = (u16*)(ws + 63176704);
  float* out = (float*)d_out;

  hipFuncSetAttribute((const void*)k_out2,
                      hipFuncAttributeMaxDynamicSharedMemorySize, LDS_OUT2_BYTES);

  k_cvt_w<<<dim3(3072), 256, 0, stream>>>(Wq, Wk, Wv, wcb);
  k_gemm<<<dim3(24, 32), 256, 0, stream>>>(hs, wcb, bq, bk, bv, qp, kp, gG, vT);
  k_cumsum<<<dim3(NC_, 2, B_), 256, 0, stream>>>(gG, dec);
  k_dstate<<<dim3(NC_, HKV_, B_), 256, 0, stream>>>(kp, gG, vT, SSt);
  k_scan<<<dim3(32, HKV_, B_), 128, 0, stream>>>(SSt, dec);
  k_out2<<<dim3(NC_, HKV_, B_), 512, LDS_OUT2_BYTES, stream>>>(qp, kp, gG, vT, SSt, out);
}

// Round 13
// 145.511 us; speedup vs baseline: 1.0566x; 1.0566x over previous
//
#include <hip/hip_runtime.h>
#include <math.h>

// ---- problem constants ----
#define B_ 2
#define S_ 2048
#define DM_ 2048
#define H_ 16
#define HKV_ 4
#define D_ 128
#define NKV_ 512           // HKV*D
#define M_ 4096            // B*S
#define CHK_ 32            // chunk length
#define NC_ 64             // S/CHK
#define SCALE_ 0.08838834764831845f
#define CLAMP_ 0.95f

typedef unsigned short u16;
typedef u16 ushortx8 __attribute__((ext_vector_type(8)));
typedef __bf16 bf16x8 __attribute__((ext_vector_type(8)));
typedef float f32x4 __attribute__((ext_vector_type(4)));

#define ASYNC16(gsrc, ldst) \
  __builtin_amdgcn_global_load_lds((const __attribute__((address_space(1))) void*)(gsrc), \
                                   (__attribute__((address_space(3))) void*)(ldst), 16, 0, 0)
#define SBAR()    __builtin_amdgcn_s_barrier()
#define WAITV(n)  asm volatile("s_waitcnt vmcnt(" #n ")" ::: "memory")

__device__ __forceinline__ u16 f2b(float x){
  unsigned u = __float_as_uint(x);
  return (u16)((u + 0x7FFFu + ((u >> 16) & 1u)) >> 16);
}
__device__ __forceinline__ float b2f(u16 h){
  return __uint_as_float(((unsigned)h) << 16);
}
__device__ __forceinline__ bf16x8 ld8(const u16* p){
  return __builtin_bit_cast(bf16x8, *(const ushortx8*)p);
}
__device__ __forceinline__ f32x4 mfma16(bf16x8 a, bf16x8 b, f32x4 c){
  return __builtin_amdgcn_mfma_f32_16x16x32_bf16(a, b, c, 0, 0, 0);
}
// scale 8 bf16 elements by 8 f32 factors, re-round to bf16
__device__ __forceinline__ bf16x8 scale8(bf16x8 v, const float* s){
  ushortx8 u = __builtin_bit_cast(ushortx8, v);
  ushortx8 o;
  #pragma unroll
  for (int j = 0; j < 8; ++j) o[j] = f2b(b2f(u[j]) * s[j]);
  return __builtin_bit_cast(bf16x8, o);
}

// ---------------- fused f32 -> bf16 convert for hs + Wq + Wk + Wv ----------------
__global__ void k_cvt_all(const float* __restrict__ hs, const float* __restrict__ Wq,
                          const float* __restrict__ Wk, const float* __restrict__ Wv,
                          u16* __restrict__ hsb, u16* __restrict__ wcb){
  int i = blockIdx.x * blockDim.x + threadIdx.x;  // 8-elem unit
  const float* src; u16* dst;
  if (i < 1048576)      { src = hs + (size_t)i * 8;               dst = hsb + (size_t)i * 8; }
  else if (i < 1572864) { int j = i - 1048576; src = Wq + (size_t)j * 8; dst = wcb + (size_t)j * 8; }
  else if (i < 1703936) { int j = i - 1572864; src = Wk + (size_t)j * 8; dst = wcb + 4194304 + (size_t)j * 8; }
  else                  { int j = i - 1703936; src = Wv + (size_t)j * 8; dst = wcb + 5242880 + (size_t)j * 8; }
  const float4* p = (const float4*)src;
  float4 a = p[0], c = p[1];
  ushortx8 o;
  o[0]=f2b(a.x); o[1]=f2b(a.y); o[2]=f2b(a.z); o[3]=f2b(a.w);
  o[4]=f2b(c.x); o[5]=f2b(c.y); o[6]=f2b(c.z); o[7]=f2b(c.w);
  *(ushortx8*)dst = o;
}

// ---------------- 128x128x32 GEMM, 3-slot LDS ring + counted vmcnt + XCD-chunked swizzle ----------------
__launch_bounds__(256, 2)
__global__ void k_gemm(const u16* __restrict__ A, const u16* __restrict__ W,
                       const float* __restrict__ bq, const float* __restrict__ bk,
                       const float* __restrict__ bv,
                       u16* __restrict__ qp, u16* __restrict__ kp,
                       float* __restrict__ gG, u16* __restrict__ vT){
  __shared__ u16 L[3 * 8192];          // 48 KiB
  const int tid = threadIdx.x;
  const int wid = tid >> 6, lane = tid & 63;
  int wg = blockIdx.x;
  wg = (wg & 7) * 96 + (wg >> 3);      // XCD-chunked, bijective (768 = 8*96)
  const int tn = wg % 24;
  const int m0 = (wg / 24) * 128, n0 = tn * 128;
  const int wr = (wid >> 1) * 64, wc = (wid & 1) * 64;
  const int lr = lane & 15;

  int offA[4], offB[4];
  #pragma unroll
  for (int m = 0; m < 4; ++m)
    offA[m] = (wr + m * 16 + lr) * 32 + (((lane >> 4) ^ (lr & 3)) << 3);
  #pragma unroll
  for (int n = 0; n < 4; ++n)
    offB[n] = (wc + n * 16 + lr) * 32 + (((lane >> 4) ^ (lr & 3)) << 3);

  const int srow = wid * 32 + (lane >> 2);
  const int scol = (((lane & 3) ^ ((lane >> 2) & 3)) << 3);
  const u16* gA = A + (size_t)(m0 + srow) * DM_ + scol;
  const u16* gW = W + (size_t)(n0 + srow) * DM_ + scol;
  const int fo = wid * 1024;

#define STG(db, kk0) \
  ASYNC16(gA + (kk0),             L + (db) + fo); \
  ASYNC16(gA + 16 * DM_ + (kk0),  L + (db) + fo + 512); \
  ASYNC16(gW + (kk0),             L + (db) + 4096 + fo); \
  ASYNC16(gW + 16 * DM_ + (kk0),  L + (db) + 4096 + fo + 512)

  f32x4 acc[4][4] = {};

  STG(0, 0);
  STG(8192, 32);

  int sl_cur = 0, sl_st = 16384;
  for (int kt = 0; kt < 64; ++kt){
    WAITV(4);
    SBAR();
    const int k2 = ((kt + 2 < 64) ? kt + 2 : 63) * 32;
    STG(sl_st, k2);
    bf16x8 af[4], bfv[4];
    #pragma unroll
    for (int m = 0; m < 4; ++m) af[m]  = ld8(L + sl_cur + offA[m]);
    #pragma unroll
    for (int n = 0; n < 4; ++n) bfv[n] = ld8(L + sl_cur + 4096 + offB[n]);
    #pragma unroll
    for (int m = 0; m < 4; ++m)
      #pragma unroll
      for (int n = 0; n < 4; ++n)
        acc[m][n] = mfma16(af[m], bfv[n], acc[m][n]);
    sl_cur = (sl_cur == 16384) ? 0 : sl_cur + 8192;
    sl_st  = (sl_st  == 16384) ? 0 : sl_st  + 8192;
  }
#undef STG

  const int lg4 = lane >> 4;
  if (tn < 16){                       // ---- q region: relu * scale ----
    #pragma unroll
    for (int i = 0; i < 4; ++i){
      const int rb = m0 + wr + i*16 + lg4*4;
      #pragma unroll
      for (int j = 0; j < 4; ++j){
        const int col = n0 + wc + j*16 + lr;
        const float bb = bq[col];
        #pragma unroll
        for (int r = 0; r < 4; ++r){
          float q = fmaxf(acc[i][j][r] + bb, 0.f) * SCALE_;
          qp[(size_t)(rb + r) * DM_ + col] = f2b(q);
        }
      }
    }
  } else if (tn < 20){                // ---- k region ----
    #pragma unroll
    for (int i = 0; i < 4; ++i){
      const int rb = m0 + wr + i*16 + lg4*4;
      #pragma unroll
      for (int j = 0; j < 4; ++j){
        const int cc = n0 - DM_ + wc + j*16 + lr;
        const float bb = bk[cc];
        #pragma unroll
        for (int r = 0; r < 4; ++r){
          float x = acc[i][j][r] + bb;
          float kf = fminf(1.f / (1.f + __expf(-x)), CLAMP_);
          kp[(size_t)(rb + r) * NKV_ + cc] = f2b(kf);
          gG[(size_t)(rb + r) * NKV_ + cc] = log1pf(-kf);
        }
      }
    }
  } else {                            // ---- v region: write transposed vT[b][kv][e][s] ----
    #pragma unroll
    for (int i = 0; i < 4; ++i){
      const int rb = m0 + wr + i*16 + lg4*4;
      const int bb_ = rb >> 11;
      const int srw = rb & 2047;
      #pragma unroll
      for (int j = 0; j < 4; ++j){
        const int cc = n0 - DM_ - NKV_ + wc + j*16 + lr;
        const float bias = bv[cc];
        const int kv = cc >> 7, e = cc & 127;
        ushort4 pk;
        pk.x = f2b(acc[i][j][0] + bias);
        pk.y = f2b(acc[i][j][1] + bias);
        pk.z = f2b(acc[i][j][2] + bias);
        pk.w = f2b(acc[i][j][3] + bias);
        *(ushort4*)(vT + (((size_t)(bb_ * HKV_ + kv) * D_ + e) * S_ + srw)) = pk;
      }
    }
  }
}

// ---------------- per-chunk inclusive cumsum of g (in place) + chunk decay ----------------
__global__ void k_cumsum(float* __restrict__ g, float* __restrict__ dec){
  const int c = blockIdx.x, b = blockIdx.z;
  const int col = blockIdx.y * 256 + threadIdx.x;   // 512 = kv*128+d
  const size_t base = ((size_t)b * S_ + (size_t)c * CHK_) * NKV_ + col;
  float v[CHK_];
  #pragma unroll
  for (int t = 0; t < CHK_; ++t) v[t] = g[base + (size_t)t * NKV_];
  float acc = 0.f;
  #pragma unroll
  for (int t = 0; t < CHK_; ++t){ acc += v[t]; v[t] = acc; }
  #pragma unroll
  for (int t = 0; t < CHK_; ++t) g[base + (size_t)t * NKV_] = v[t];
  const int kv = col >> 7, d = col & 127;
  dec[(((size_t)b * HKV_ + kv) * NC_ + c) * D_ + d] = __expf(acc);
}

// ---------------- per-chunk state contribution:  SSt[c][e][d] = sum_t v[t][e]*kf[t][d]*exp(G31-G_t) ----------------
__launch_bounds__(256, 2)
__global__ void k_dstate(const u16* __restrict__ kp, const float* __restrict__ G,
                         const u16* __restrict__ vT, u16* __restrict__ SSt){
  __shared__ float kex[CHK_][D_];
  __shared__ float vl[D_][CHK_ + 1];
  const int c = blockIdx.x, kv = blockIdx.y, b = blockIdx.z;
  const int tid = threadIdx.x;
  const int s0 = c * CHK_;
  const size_t gbase = ((size_t)b * S_ + s0) * NKV_ + kv * D_;
  for (int idx = tid; idx < CHK_ * D_; idx += 256){
    const int t = idx >> 7, d = idx & 127;
    const float Gt  = G[gbase + (size_t)t  * NKV_ + d];
    const float G31 = G[gbase + (size_t)31 * NKV_ + d];
    const float kf = b2f(kp[gbase + (size_t)t * NKV_ + d]);
    kex[t][d] = kf * __expf(G31 - Gt);
  }
  const size_t vbase = ((size_t)(b * HKV_ + kv) * D_) * S_ + s0;
  for (int idx = tid; idx < 512; idx += 256){
    const int e = idx >> 2, t8 = (idx & 3) * 8;
    ushortx8 vv = *(const ushortx8*)(vT + vbase + (size_t)e * S_ + t8);
    #pragma unroll
    for (int u = 0; u < 8; ++u) vl[e][t8 + u] = b2f(vv[u]);
  }
  __syncthreads();
  const int w = tid >> 6, lane = tid & 63;
  const int e = (w & 1) * 64 + lane;
  const int d0 = (w >> 1) * 64;
  float acc[64];
  #pragma unroll
  for (int i = 0; i < 64; ++i) acc[i] = 0.f;
  for (int t = 0; t < CHK_; ++t){
    const float vv = vl[e][t];
    const float4* kr = (const float4*)(&kex[t][d0]);
    #pragma unroll
    for (int i4 = 0; i4 < 16; ++i4){
      float4 kk = kr[i4];
      acc[i4*4+0] = fmaf(vv, kk.x, acc[i4*4+0]);
      acc[i4*4+1] = fmaf(vv, kk.y, acc[i4*4+1]);
      acc[i4*4+2] = fmaf(vv, kk.z, acc[i4*4+2]);
      acc[i4*4+3] = fmaf(vv, kk.w, acc[i4*4+3]);
    }
  }
  const size_t ob = (((size_t)(b * HKV_ + kv) * NC_ + c) * D_ + e) * D_ + d0;
  #pragma unroll
  for (int i8 = 0; i8 < 8; ++i8){
    ushortx8 o;
    #pragma unroll
    for (int u = 0; u < 8; ++u) o[u] = f2b(acc[i8*8 + u]);
    *(ushortx8*)(SSt + ob + i8*8) = o;
  }
}

// ---------------- elementwise scan over chunks (256 blocks x 128 thr, 1/CU) ----------------
__global__ void k_scan(u16* __restrict__ SSt, const float* __restrict__ dec){
  const int eg = blockIdx.x, kv = blockIdx.y, b = blockIdx.z;
  const int tid = threadIdx.x;
  const int e = eg * 4 + (tid >> 5);
  const int d4 = (tid & 31) * 4;
  const size_t base  = ((size_t)(b * HKV_ + kv) * NC_) * D_ * D_ + (size_t)e * D_ + d4;
  const size_t dbase = ((size_t)(b * HKV_ + kv) * NC_) * D_ + d4;
  float s0 = 0.f, s1 = 0.f, s2 = 0.f, s3 = 0.f;
  #pragma unroll 4
  for (int c = 0; c < NC_; ++c){
    const size_t off = base + (size_t)c * (D_ * D_);
    ushort4 dv = *(ushort4*)(SSt + off);
    float4 dc = *(const float4*)(dec + dbase + (size_t)c * D_);
    ushort4 wr;
    wr.x = f2b(s0); wr.y = f2b(s1); wr.z = f2b(s2); wr.w = f2b(s3);
    *(ushort4*)(SSt + off) = wr;
    s0 = s0 * dc.x + b2f(dv.x);
    s1 = s1 * dc.y + b2f(dv.y);
    s2 = s2 * dc.z + b2f(dv.z);
    s3 = s3 * dc.w + b2f(dv.w);
  }
}

// ---------------- output, per-kv blocks; 72.5 KB LDS -> 2 blocks/CU (R11-proven) ----------------
#define L_SB   0
#define L_QEF  16384
#define L_KE1  32768
#define L_SF   36864
#define LDS_OUT2_BYTES ((36864 + 256) * 2)
__global__ void __launch_bounds__(512)
k_out2(const u16* __restrict__ qp, const u16* __restrict__ kp,
       const float* __restrict__ G, const u16* __restrict__ vT,
       const u16* __restrict__ SSt, float* __restrict__ out){
  extern __shared__ u16 lds[];
  float* sFf = (float*)(lds + L_SF);
  const int c = blockIdx.x, kv = blockIdx.y, b = blockIdx.z;
  const int tid = threadIdx.x, wid = tid >> 6, lane = tid & 63;
  const int hh = wid >> 1, sub = wid & 1;
  const int s0 = c * CHK_;
  const int lr = lane & 15, lk = (lane >> 4) * 8;
  const size_t gb = ((size_t)b * S_ + s0) * NKV_ + kv * D_;
  const size_t qb0 = ((size_t)b * S_ + s0) * DM_ + (kv * 4) * D_;
  const size_t vb = ((size_t)(b * HKV_ + kv) * D_) * S_ + s0;

  {
    const u16* src = SSt + (((size_t)(b * HKV_ + kv) * NC_ + c) * (D_ * D_));
    #pragma unroll
    for (int is = 0; is < 4; ++is){
      const int fo = is * 4096 + wid * 512;
      ASYNC16(src + fo + lane * 8, lds + L_SB + fo);
    }
  }
  const int dmy = tid & 127;
  const float G15v = G[gb + (size_t)15 * NKV_ + dmy];
  if (tid < 128) sFf[tid] = __expf(-G15v);

  for (int idx = tid; idx < 32 * 128; idx += 512){
    const int t = idx >> 7;
    const float Gt = G[gb + (size_t)t * NKV_ + dmy];
    const float kf = b2f(kp[gb + (size_t)t * NKV_ + dmy]);
    const float eGt = __expf(Gt);
    float qv[4];
    #pragma unroll
    for (int q4 = 0; q4 < 4; ++q4) qv[q4] = b2f(qp[qb0 + (size_t)t * DM_ + q4 * D_ + dmy]);
    #pragma unroll
    for (int q4 = 0; q4 < 4; ++q4) lds[L_QEF + q4 * 4096 + idx] = f2b(qv[q4] * eGt);
    lds[L_KE1 + idx] = f2b(kf * __expf(G15v - Gt));
  }
  __syncthreads();

  float sreg[4][8];
  #pragma unroll
  for (int kd = 0; kd < 4; ++kd)
    #pragma unroll
    for (int j = 0; j < 8; ++j) sreg[kd][j] = sFf[kd * 32 + lk + j];

  const u16* QeF = lds + L_QEF + hh * 4096;
  const u16* KE1 = lds + L_KE1;
  f32x4 aU = {}, aL = {}, aO = {};
  if (sub == 0){
    #pragma unroll
    for (int kd = 0; kd < 4; ++kd){
      bf16x8 faU = ld8(&QeF[lr * 128 + kd * 32 + lk]);
      bf16x8 fbU = scale8(ld8(&KE1[lr * 128 + kd * 32 + lk]), sreg[kd]);
      aU = mfma16(faU, fbU, aU);
      bf16x8 faL = scale8(ld8(&QeF[(16 + lr) * 128 + kd * 32 + lk]), sreg[kd]);
      bf16x8 fbL = ld8(&KE1[(16 + lr) * 128 + kd * 32 + lk]);
      aL = mfma16(faL, fbL, aL);
    }
  } else {
    #pragma unroll
    for (int kd = 0; kd < 4; ++kd){
      bf16x8 fa = ld8(&QeF[(16 + lr) * 128 + kd * 32 + lk]);
      fa = scale8(fa, sreg[kd]);
      bf16x8 fb = ld8(&KE1[lr * 128 + kd * 32 + lk]);
      aO = mfma16(fa, fb, aO);
    }
  }
  __syncthreads();

  u16* Am = lds + L_KE1 + hh * 1024;
  if (sub == 0){
    #pragma unroll
    for (int r = 0; r < 4; ++r){
      const int rr = (lane >> 4) * 4 + r;
      float vU = aU[r]; if (lr > rr) vU = 0.f;
      Am[rr * 32 + lr] = f2b(vU);
      float vL = aL[r]; if (lr > rr) vL = 0.f;
      Am[(16 + rr) * 32 + 16 + lr] = f2b(vL);
    }
  } else {
    #pragma unroll
    for (int r = 0; r < 4; ++r){
      const int rr = (lane >> 4) * 4 + r;
      Am[(16 + rr) * 32 + lr] = f2b(aO[r]);
    }
    for (int i = lane; i < 256; i += 64) Am[(i >> 4) * 32 + 16 + (i & 15)] = 0;
  }
  __syncthreads();

  f32x4 o4[2][4] = {};
  const int ew = sub * 64;
  #pragma unroll
  for (int kd = 0; kd < 4; ++kd){
    bf16x8 fa0 = ld8(&QeF[(0  + lr) * 128 + kd * 32 + lk]);
    bf16x8 fa1 = ld8(&QeF[(16 + lr) * 128 + kd * 32 + lk]);
    #pragma unroll
    for (int j2 = 0; j2 < 4; ++j2){
      bf16x8 fb = ld8(&lds[L_SB + (ew + j2 * 16 + lr) * 128 + kd * 32 + lk]);
      o4[0][j2] = mfma16(fa0, fb, o4[0][j2]);
      o4[1][j2] = mfma16(fa1, fb, o4[1][j2]);
    }
  }
  {
    bf16x8 fa0 = ld8(&Am[lr * 32 + lk]);
    bf16x8 fa1 = ld8(&Am[(16 + lr) * 32 + lk]);
    #pragma unroll
    for (int j2 = 0; j2 < 4; ++j2){
      const u16* vr = vT + vb + (size_t)(ew + j2 * 16 + lr) * S_;
      bf16x8 fb = ld8(vr + lk);
      o4[0][j2] = mfma16(fa0, fb, o4[0][j2]);
      o4[1][j2] = mfma16(fa1, fb, o4[1][j2]);
    }
  }
  const int hD = (kv * 4 + hh) * D_;
  #pragma unroll
  for (int i2 = 0; i2 < 2; ++i2)
    #pragma unroll
    for (int j2 = 0; j2 < 4; ++j2)
      #pragma unroll
      for (int r = 0; r < 4; ++r){
        const int t = i2 * 16 + (lane >> 4) * 4 + r;
        const int e = ew + j2 * 16 + lr;
        out[((size_t)b * S_ + s0 + t) * DM_ + hD + e] = o4[i2][j2][r];
      }
}

// ---------------- host launch ----------------
extern "C" void kernel_launch(void* const* d_in, const int* in_sizes, int n_in,
                              void* d_out, int out_size, void* d_ws, size_t ws_size,
                              hipStream_t stream){
  const float* hs = (const float*)d_in[0];
  const float* Wq = (const float*)d_in[1];
  const float* bq = (const float*)d_in[2];
  const float* Wk = (const float*)d_in[3];
  const float* bk = (const float*)d_in[4];
  const float* Wv = (const float*)d_in[5];
  const float* bv = (const float*)d_in[6];
  char* ws = (char*)d_ws;
  u16*   hsb = (u16*)(ws);
  u16*   wcb = (u16*)(ws + 16777216);
  u16*   qp  = (u16*)(ws + 29360128);
  u16*   kp  = (u16*)(ws + 46137344);
  float* gG  = (float*)(ws + 50331648);
  u16*   vT  = (u16*)(ws + 58720256);
  float* dec = (float*)(ws + 62914560);
  u16*   SSt = (u16*)(ws + 63176704);
  float* out = (float*)d_out;

  hipFuncSetAttribute((const void*)k_out2,
                      hipFuncAttributeMaxDynamicSharedMemorySize, LDS_OUT2_BYTES);

  k_cvt_all<<<dim3(7168), 256, 0, stream>>>(hs, Wq, Wk, Wv, hsb, wcb);
  k_gemm<<<dim3(768), 256, 0, stream>>>(hsb, wcb, bq, bk, bv, qp, kp, gG, vT);
  k_cumsum<<<dim3(NC_, 2, B_), 256, 0, stream>>>(gG, dec);
  k_dstate<<<dim3(NC_, HKV_, B_), 256, 0, stream>>>(kp, gG, vT, SSt);
  k_scan<<<dim3(32, HKV_, B_), 128, 0, stream>>>(SSt, dec);
  k_out2<<<dim3(NC_, HKV_, B_), 512, LDS_OUT2_BYTES, stream>>>(qp, kp, gG, vT, SSt, out);
}